// Round 3
// baseline (257.192 us; speedup 1.0000x reference)
//
#include <hip/hip_runtime.h>
#include <hip/hip_bf16.h>

typedef __hip_bfloat16 BF;
typedef __attribute__((ext_vector_type(8))) short bf16x8;
typedef __attribute__((ext_vector_type(4))) float f32x4;
typedef __attribute__((ext_vector_type(4))) unsigned short us4;

// B=2, C=128, H=W=128, K=8, STRIDE=2, DIL=2, NH=8, dh=16, HID=170, Hc=Wc=64
// fp32 in / fp32 out. MFMA (bf16, fp32 acc) for dense GEMMs AND attention QK/PV.
// ws (floats): xt[0,4194304) kcb[+1048576) vcb[+1048576) ; packs (bf16) at 6291456

#define ASTR 200   // k_cell Abuf row stride (bf16)
#define KSTR 136   // k_pre(kv) Abuf row stride (bf16)

// fast f32 -> bf16 (RNE) returning raw bits
__device__ __forceinline__ short bfr(float f){
  union{float f; unsigned u;} c; c.f = f;
  const unsigned u = c.u + 0x7FFFu + ((c.u >> 16) & 1u);
  return (short)(u >> 16);
}
__device__ __forceinline__ bf16x8 pk8(float4 a, float4 b){
  bf16x8 r;
  r[0]=bfr(a.x); r[1]=bfr(a.y); r[2]=bfr(a.z); r[3]=bfr(a.w);
  r[4]=bfr(b.x); r[5]=bfr(b.y); r[6]=bfr(b.z); r[7]=bfr(b.w);
  return r;
}

// ---- 2-wave (128-thr) reductions for k_cell ----
__device__ __forceinline__ void gsum16(float v[16], float* red){
  #pragma unroll
  for(int s = 1; s < 64; s <<= 1){
    #pragma unroll
    for(int i = 0; i < 16; i++) v[i] += __shfl_xor(v[i], s);
  }
  const int wid = threadIdx.x >> 6;
  __syncthreads();
  if((threadIdx.x & 63) == 0){
    #pragma unroll
    for(int i = 0; i < 16; i++) red[wid*16 + i] = v[i];
  }
  __syncthreads();
  #pragma unroll
  for(int i = 0; i < 16; i++) v[i] = red[i] + red[16 + i];
}

__device__ __forceinline__ void rowred(float s1[4], float s2[4], float* red,
                                       int wave, int lane){
  #pragma unroll
  for(int m = 1; m < 16; m <<= 1){
    #pragma unroll
    for(int r = 0; r < 4; r++){ s1[r] += __shfl_xor(s1[r], m); s2[r] += __shfl_xor(s2[r], m); }
  }
  const int q4 = lane >> 4;
  __syncthreads();
  if((lane & 15) == 0){
    #pragma unroll
    for(int r = 0; r < 4; r++){
      red[wave*32 + q4*4 + r]      = s1[r];
      red[wave*32 + 16 + q4*4 + r] = s2[r];
    }
  }
  __syncthreads();
  #pragma unroll
  for(int r = 0; r < 4; r++){
    s1[r] = red[q4*4 + r]      + red[32 + q4*4 + r];
    s2[r] = red[16 + q4*4 + r] + red[48 + q4*4 + r];
  }
}

// ---- per-half (128-thr half of a 256-thr block) reductions for k_pre/kv ----
__device__ __forceinline__ void gsum16h(float v[16], float* red, int tid){
  #pragma unroll
  for(int s = 1; s < 64; s <<= 1){
    #pragma unroll
    for(int i = 0; i < 16; i++) v[i] += __shfl_xor(v[i], s);
  }
  const int wid = tid >> 6, half = tid >> 7;
  __syncthreads();
  if((tid & 63) == 0){
    #pragma unroll
    for(int i = 0; i < 16; i++) red[wid*16 + i] = v[i];
  }
  __syncthreads();
  #pragma unroll
  for(int i = 0; i < 16; i++) v[i] = red[half*32 + i] + red[half*32 + 16 + i];
}

__device__ __forceinline__ void rowredh(float s1[4], float s2[4], float* red, int tid){
  const int lane = tid & 63, wid = tid >> 6, half = tid >> 7;
  #pragma unroll
  for(int m = 1; m < 16; m <<= 1){
    #pragma unroll
    for(int r = 0; r < 4; r++){ s1[r] += __shfl_xor(s1[r], m); s2[r] += __shfl_xor(s2[r], m); }
  }
  const int q4 = lane >> 4;
  __syncthreads();
  if((lane & 15) == 0){
    #pragma unroll
    for(int r = 0; r < 4; r++){
      red[wid*32 + q4*4 + r]      = s1[r];
      red[wid*32 + 16 + q4*4 + r] = s2[r];
    }
  }
  __syncthreads();
  #pragma unroll
  for(int r = 0; r < 4; r++){
    s1[r] = red[half*64 + q4*4 + r]      + red[half*64 + 32 + q4*4 + r];
    s2[r] = red[half*64 + 16 + q4*4 + r] + red[half*64 + 48 + q4*4 + r];
  }
}

// ---- K_pre: fused {transpose x->xt | weight pack | coarse k,v} ----
// blocks [0,4096): tiled transpose; [4096,4536): weight pack; [4536,5048): kv.
// kv blocks read x DIRECTLY (thread=channel reads its own 64B row segment), so
// all three parts are independent and overlap in one launch.
__global__ void __launch_bounds__(256)
k_pre(const float* __restrict__ x,
      const float* __restrict__ qkv_w, const float* __restrict__ proj_w,
      const float* __restrict__ fc1_w, const float* __restrict__ fc2_w,
      const float* __restrict__ qkv_b,
      const float* __restrict__ kg, const float* __restrict__ kb,
      const float* __restrict__ n1g, const float* __restrict__ n1b,
      float* __restrict__ xt, BF* __restrict__ pk,
      float* __restrict__ kcb, float* __restrict__ vcb){
  __shared__ __align__(16) unsigned char sm[9216];
  const int bx = blockIdx.x, tid = threadIdx.x;

  if(bx < 4096){                       // ---- transpose x (B,C,H,W) -> xt (B,HW,C)
    float (*tile)[33] = (float(*)[33])sm;
    const int b = bx >> 11, r2 = bx & 2047;
    const int pb = (r2 >> 2) * 32, cb = (r2 & 3) * 32;
    const int tx = tid & 31, ty = tid >> 5;
    #pragma unroll
    for(int r = 0; r < 32; r += 8)
      tile[ty+r][tx] = x[(size_t)(b*128 + cb+ty+r)*16384 + pb + tx];
    __syncthreads();
    #pragma unroll
    for(int r = 0; r < 32; r += 8)
      xt[(size_t)((b<<14) + pb + ty + r)*128 + cb + tx] = tile[tx][ty+r];
    return;
  }
  if(bx < 4536){                       // ---- weight pack
    const int idx = (bx - 4096) * 256 + tid;
    if(idx >= 112640) return;
    float val;
    if(idx < 49152){
      const int reg = idx >> 14, l = idx & 16383;
      const int j = l & 7, q = (l>>3)&3, n = (l>>5)&127, s = l>>12;
      val = qkv_w[(reg*128 + n)*128 + (s*32 + q*8 + j)];
    } else if(idx < 65536){
      const int l = idx - 49152;
      const int j = l&7, q=(l>>3)&3, n=(l>>5)&127, s=l>>12;
      val = proj_w[n*128 + (s*32+q*8+j)];
    } else if(idx < 88064){
      const int l = idx - 65536;
      const int j = l&7, q=(l>>3)&3, rem = l>>5;
      const int n = rem % 176, s = rem / 176;
      const int k = s*32+q*8+j;
      val = (n < 170) ? fc1_w[n*128 + k] : 0.f;
    } else {
      const int l = idx - 88064;
      const int j = l&7, q=(l>>3)&3, n=(l>>5)&127, s=l>>12;
      const int k = s*32+q*8+j;
      val = (k < 170) ? fc2_w[n*170 + k] : 0.f;
    }
    pk[idx] = __float2bfloat16(val);
    return;
  }

  // ---- kv: 16 coarse px/block, two independent 128-thr halves ----
  const BF* packK = pk + 16384;
  const BF* packV = pk + 32768;
  BF* const Abuf = (BF*)sm;                    // 2 halves x [16][KSTR]
  float* const red = (float*)(sm + 8704);      // 128 floats
  const int bx2 = bx - 4536;
  const int lane = tid & 63, half = tid >> 7, wh = (tid >> 6) & 1, c = tid & 127;
  const int l15 = lane & 15, q4 = lane >> 4;
  const int cp0 = bx2 * 16;
  const int b = cp0 >> 12, ic = (cp0 & 4095) >> 6, jb = cp0 & 63;
  BF* const AbufH = Abuf + half*16*KSTR;

  float xv[8];
  {
    const size_t off = (size_t)(b*128 + c)*16384 + (size_t)(2*ic)*128 + 2*(jb + half*8);
    const float4* xp4 = (const float4*)(x + off);
    const float4 f0 = xp4[0], f1 = xp4[1], f2 = xp4[2], f3 = xp4[3];
    xv[0]=f0.x; xv[1]=f0.z; xv[2]=f1.x; xv[3]=f1.z;
    xv[4]=f2.x; xv[5]=f2.z; xv[6]=f3.x; xv[7]=f3.z;
  }
  float st[16];
  #pragma unroll
  for(int r = 0; r < 8; r++){ st[r] = xv[r]; st[8+r] = xv[r]*xv[r]; }
  gsum16h(st, red, tid);
  {
    const float g = n1g[c], be = n1b[c];
    #pragma unroll
    for(int r = 0; r < 8; r++){
      const float mu = st[r]*(1.f/128.f);
      const float var = st[8+r]*(1.f/128.f) - mu*mu;
      AbufH[r*KSTR + c] = __float2bfloat16((xv[r]-mu)*rsqrtf(var+1e-6f)*g + be);
    }
  }
  __syncthreads();
  bf16x8 af[4];
  #pragma unroll
  for(int s = 0; s < 4; s++) af[s] = *(const bf16x8*)&AbufH[l15*KSTR + s*32 + q4*8];

  // ---- k GEMM ----
  f32x4 acc[4];
  #pragma unroll
  for(int nt = 0; nt < 4; nt++){ acc[nt][0]=0.f; acc[nt][1]=0.f; acc[nt][2]=0.f; acc[nt][3]=0.f; }
  #pragma unroll
  for(int nt = 0; nt < 4; nt++){
    const int n = (wh*4+nt)*16 + l15;
    #pragma unroll
    for(int s = 0; s < 4; s++){
      bf16x8 bf = *(const bf16x8*)&packK[((s*128 + n)*4 + q4)*8];
      acc[nt] = __builtin_amdgcn_mfma_f32_16x16x32_bf16(af[s], bf, acc[nt], 0,0,0);
    }
  }
  float s1[4], s2[4];
  #pragma unroll
  for(int r = 0; r < 4; r++){ s1[r]=0.f; s2[r]=0.f; }
  #pragma unroll
  for(int nt = 0; nt < 4; nt++){
    const float colb = qkv_b[128 + (wh*4+nt)*16 + l15];
    #pragma unroll
    for(int r = 0; r < 4; r++){
      const float vv = acc[nt][r] + colb;
      acc[nt][r] = vv; s1[r] += vv; s2[r] += vv*vv;
    }
  }
  rowredh(s1, s2, red, tid);
  #pragma unroll
  for(int nt = 0; nt < 4; nt++){
    const int col = (wh*4+nt)*16 + l15;
    const float g = kg[col], be = kb[col];
    #pragma unroll
    for(int r = 0; r < 4; r++){
      const int row = q4*4 + r;
      if(row < 8){
        const float mu = s1[r]*(1.f/128.f);
        const float var = s2[r]*(1.f/128.f) - mu*mu;
        kcb[(size_t)(cp0 + half*8 + row)*128 + col] = (acc[nt][r]-mu)*rsqrtf(var+1e-6f)*g + be;
      }
    }
  }
  // ---- v GEMM ----
  #pragma unroll
  for(int nt = 0; nt < 4; nt++){ acc[nt][0]=0.f; acc[nt][1]=0.f; acc[nt][2]=0.f; acc[nt][3]=0.f; }
  #pragma unroll
  for(int nt = 0; nt < 4; nt++){
    const int n = (wh*4+nt)*16 + l15;
    #pragma unroll
    for(int s = 0; s < 4; s++){
      bf16x8 bf = *(const bf16x8*)&packV[((s*128 + n)*4 + q4)*8];
      acc[nt] = __builtin_amdgcn_mfma_f32_16x16x32_bf16(af[s], bf, acc[nt], 0,0,0);
    }
  }
  #pragma unroll
  for(int nt = 0; nt < 4; nt++){
    const int col = (wh*4+nt)*16 + l15;
    const float bv = qkv_b[256 + col];
    #pragma unroll
    for(int r = 0; r < 4; r++){
      const int row = q4*4 + r;
      if(row < 8) vcb[(size_t)(cp0 + half*8 + row)*128 + col] = acc[nt][r] + bv;
    }
  }
}

// ---- K_cell: fused per-2-cells (8 pixels) block, all-MFMA ----
// LDS budget (~16.3KB -> 10 blocks/CU): uni 13824 + qnH 2176 (red aliased in) +
// cidx 256. Output stored directly in (B,C,H,W) layout (k_tout eliminated).
__global__ void __launch_bounds__(128, 5)
k_cell(const float* __restrict__ xt_in,
       const BF* __restrict__ packQ, const BF* __restrict__ packP,
       const BF* __restrict__ packF1, const BF* __restrict__ packF2,
       const float* __restrict__ qkv_b,
       const float* __restrict__ qg, const float* __restrict__ qb,
       const float* __restrict__ n1g, const float* __restrict__ n1b,
       const float* __restrict__ proj_b,
       const float* __restrict__ ls1, const float* __restrict__ ls2,
       const float* __restrict__ n2g, const float* __restrict__ n2b,
       const float* __restrict__ fc1_b,
       const float* __restrict__ mg, const float* __restrict__ mb,
       const float* __restrict__ fc2_b,
       const float* __restrict__ kcb, const float* __restrict__ vcb,
       float* __restrict__ out){
  __shared__ __align__(16) BF uni[6912];      // Abuf[16][ASTR] U per-wave attn {Vt,Pb}
  BF* const Abuf = uni;
  __shared__ __align__(16) ushort qnH[1088];  // [cell][136ch_pad][4px] bf16 (red aliases first 256B)
  __shared__ ushort cidx2[128];               // [cell][64] safe coarse-px linear idx
  float* const red = (float*)qnH;
  const int tid = threadIdx.x, wave = tid>>6, lane = tid&63;
  const int l15 = lane & 15, q4 = lane >> 4;

  const int bx = blockIdx.x;
  const int b = bx >> 11, rem = bx & 2047, ip = rem >> 6, jc = rem & 63;
  const int icA = 2*ip, icB = 2*ip + 1;
  const size_t p0 = (size_t)b*16384*128 + ((size_t)(4*ip)*128 + 2*jc)*128;
  float xv[8];
  #pragma unroll
  for(int r = 0; r < 8; r++){
    const size_t pr = p0 + ((size_t)(r>>1)<<14) + (size_t)((r&1)<<7);
    xv[r] = xt_in[pr + tid];
  }

  // ---- LN1 (single fused reduction) ----
  float st[16];
  #pragma unroll
  for(int r = 0; r < 8; r++){ st[r] = xv[r]; st[8+r] = xv[r]*xv[r]; }
  gsum16(st, red);
  {
    const float g = n1g[tid], be = n1b[tid];
    #pragma unroll
    for(int r = 0; r < 8; r++){
      const float mu = st[r]*(1.f/128.f);
      const float var = st[8+r]*(1.f/128.f) - mu*mu;
      Abuf[r*ASTR + tid] = __float2bfloat16((xv[r]-mu)*rsqrtf(var+1e-6f)*g + be);
    }
  }
  if(tid < 64){
    const int i = tid >> 3, j = tid & 7;
    const int rj0 = jc + 2*j - 8;
    const bool vj0 = (rj0 >= 0) && (rj0 < 64);
    const int riA = icA + 2*i - 8, riB = icB + 2*i - 8;
    cidx2[tid]      = (vj0 && riA >= 0 && riA < 64) ? (ushort)(b*4096 + riA*64 + rj0) : (ushort)0;
    cidx2[64 + tid] = (vj0 && riB >= 0 && riB < 64) ? (ushort)(b*4096 + riB*64 + rj0) : (ushort)0;
  }
  __syncthreads();

  // ---- q GEMM + q-LN -> qnH (bf16) ----
  {
    bf16x8 af[4];
    #pragma unroll
    for(int s = 0; s < 4; s++) af[s] = *(const bf16x8*)&Abuf[l15*ASTR + s*32 + q4*8];
    f32x4 acc[4];
    #pragma unroll
    for(int nt = 0; nt < 4; nt++){ acc[nt][0]=0.f; acc[nt][1]=0.f; acc[nt][2]=0.f; acc[nt][3]=0.f; }
    #pragma unroll
    for(int nt = 0; nt < 4; nt++){
      const int n = (wave*4+nt)*16 + l15;
      #pragma unroll
      for(int s = 0; s < 4; s++){
        bf16x8 bf = *(const bf16x8*)&packQ[((s*128 + n)*4 + q4)*8];
        acc[nt] = __builtin_amdgcn_mfma_f32_16x16x32_bf16(af[s], bf, acc[nt], 0,0,0);
      }
    }
    float s1[4], s2[4];
    #pragma unroll
    for(int r = 0; r < 4; r++){ s1[r]=0.f; s2[r]=0.f; }
    #pragma unroll
    for(int nt = 0; nt < 4; nt++){
      const float cb2 = qkv_b[(wave*4+nt)*16 + l15];
      #pragma unroll
      for(int r = 0; r < 4; r++){
        const float vv = acc[nt][r] + cb2;
        acc[nt][r] = vv; s1[r] += vv; s2[r] += vv*vv;
      }
    }
    rowred(s1, s2, red, wave, lane);
    const bool wq = (q4 < 2);
    us4 tw[4];
    if(wq){
      float mu[4], rs[4];
      #pragma unroll
      for(int r = 0; r < 4; r++){
        mu[r] = s1[r]*(1.f/128.f);
        rs[r] = rsqrtf(s2[r]*(1.f/128.f) - mu[r]*mu[r] + 1e-6f);
      }
      #pragma unroll
      for(int nt = 0; nt < 4; nt++){
        const int col = (wave*4+nt)*16 + l15;
        const float g = qg[col], be = qb[col];
        tw[nt][0] = (unsigned short)bfr((acc[nt][0]-mu[0])*rs[0]*g + be);
        tw[nt][1] = (unsigned short)bfr((acc[nt][1]-mu[1])*rs[1]*g + be);
        tw[nt][2] = (unsigned short)bfr((acc[nt][2]-mu[2])*rs[2]*g + be);
        tw[nt][3] = (unsigned short)bfr((acc[nt][3]-mu[3])*rs[3]*g + be);
      }
    }
    __syncthreads();            // red (aliased with qnH) fully read by all waves
    if(wq){
      #pragma unroll
      for(int nt = 0; nt < 4; nt++){
        const int col = (wave*4+nt)*16 + l15;
        const int colp = col + (col >> 4);
        *(us4*)(qnH + q4*544 + colp*4) = tw[nt];
      }
    }
  }
  __syncthreads();

  // ---- attention, all-MFMA, wave-private heads ----
  const int g = wave;
  const int hsub = l15 >> 2, px = l15 & 3;
  const int par = q4 >> 1, dbase = (q4 & 1) * 8;
  BF* const attw = uni + wave*3456;
  ushort* const Vt = (ushort*)attw;            // 2 slots x [16][72]
  ushort* const Pb = (ushort*)(attw + 2304);   // [16][72]
  const int i0 = l15 >> 3;
  const int rj = jc + 2*(l15 & 7) - 8;
  const bool vj = (rj >= 0) && (rj < 64);

  f32x4 oC[2];
  #pragma unroll
  for(int cell = 0; cell < 2; cell++){
    const ushort* cidx = cidx2 + cell*64;
    const ushort* qp = qnH + cell*544;
    const int ic = cell ? icB : icA;
    float madd[4];
    #pragma unroll
    for(int nt = 0; nt < 4; nt++){
      const int ri = ic + 2*(nt*2 + i0) - 8;
      madd[nt] = (vj && ri >= 0 && ri < 64) ? 0.f : -1e30f;
    }
    // block-diagonal q A-fragments
    bf16x8 afq0, afq1;
    {
      const int idx0 = (g*64 + hsub*16 + dbase + (g*4 + hsub))*4 + px;
      short bq[8];
      #pragma unroll
      for(int j = 0; j < 8; j++) bq[j] = (short)qp[idx0 + 4*j];
      const bool a0 = (par == hsub), a1 = ((2 + par) == hsub);
      #pragma unroll
      for(int j = 0; j < 8; j++){
        afq0[j] = a0 ? bq[j] : (short)0;
        afq1[j] = a1 ? bq[j] : (short)0;
      }
    }
    // ---- QK: 8 MFMA ----
    f32x4 accq[4];
    #pragma unroll
    for(int nt = 0; nt < 4; nt++){ accq[nt][0]=0.f; accq[nt][1]=0.f; accq[nt][2]=0.f; accq[nt][3]=0.f; }
    #pragma unroll
    for(int nt = 0; nt < 4; nt++){
      const float* kp = kcb + ((size_t)cidx[nt*16 + l15] << 7) + g*64 + q4*8;
      const float4 k00 = *(const float4*)kp;
      const float4 k01 = *(const float4*)(kp + 4);
      const float4 k10 = *(const float4*)(kp + 32);
      const float4 k11 = *(const float4*)(kp + 36);
      accq[nt] = __builtin_amdgcn_mfma_f32_16x16x32_bf16(afq0, pk8(k00,k01), accq[nt], 0,0,0);
      accq[nt] = __builtin_amdgcn_mfma_f32_16x16x32_bf16(afq1, pk8(k10,k11), accq[nt], 0,0,0);
    }
    // ---- softmax in-register; unnormalized e (bf16) -> Pb ----
    float inv[4];
    #pragma unroll
    for(int reg = 0; reg < 4; reg++){
      const float s0 = accq[0][reg]*0.25f + madd[0];
      const float s1 = accq[1][reg]*0.25f + madd[1];
      const float s2 = accq[2][reg]*0.25f + madd[2];
      const float s3 = accq[3][reg]*0.25f + madd[3];
      float m = fmaxf(fmaxf(s0,s1), fmaxf(s2,s3));
      #pragma unroll
      for(int sft = 1; sft < 16; sft <<= 1) m = fmaxf(m, __shfl_xor(m, sft));
      const float e0 = __expf(s0-m), e1 = __expf(s1-m);
      const float e2 = __expf(s2-m), e3 = __expf(s3-m);
      ushort* pr = Pb + (q4*4 + reg)*72 + l15;
      pr[0]  = (ushort)bfr(e0);
      pr[16] = (ushort)bfr(e1);
      pr[32] = (ushort)bfr(e2);
      pr[48] = (ushort)bfr(e3);
      float es = e0+e1+e2+e3;
      #pragma unroll
      for(int sft = 1; sft < 16; sft <<= 1) es += __shfl_xor(es, sft);
      inv[reg] = 1.f/es;
    }
    const bf16x8 pa0 = *(const bf16x8*)(Pb + l15*72 + q4*8);
    const bf16x8 pa1 = *(const bf16x8*)(Pb + l15*72 + 32 + q4*8);

    // ---- PV: stage V (packed ushort4 writes) + 2 MFMA per head ----
    f32x4 oSel; oSel[0]=0.f; oSel[1]=0.f; oSel[2]=0.f; oSel[3]=0.f;
    #pragma unroll
    for(int pr2 = 0; pr2 < 2; pr2++){
      #pragma unroll
      for(int sl = 0; sl < 2; sl++){
        const int h = g*4 + pr2*2 + sl;
        float4 vv[4];
        #pragma unroll
        for(int it = 0; it < 4; it++)
          vv[it] = *(const float4*)(vcb + ((size_t)cidx[l15*4 + it] << 7) + h*16 + q4*4);
        #pragma unroll
        for(int dd = 0; dd < 4; dd++){
          us4 w;
          w[0] = (unsigned short)bfr(((const float*)&vv[0])[dd]);
          w[1] = (unsigned short)bfr(((const float*)&vv[1])[dd]);
          w[2] = (unsigned short)bfr(((const float*)&vv[2])[dd]);
          w[3] = (unsigned short)bfr(((const float*)&vv[3])[dd]);
          *(us4*)(Vt + sl*1152 + (q4*4 + dd)*72 + l15*4) = w;
        }
      }
      #pragma unroll
      for(int sl = 0; sl < 2; sl++){
        const int hs = pr2*2 + sl;
        const bf16x8 bv0 = *(const bf16x8*)(Vt + sl*1152 + l15*72 + q4*8);
        const bf16x8 bv1 = *(const bf16x8*)(Vt + sl*1152 + l15*72 + 32 + q4*8);
        f32x4 accv; accv[0]=0.f; accv[1]=0.f; accv[2]=0.f; accv[3]=0.f;
        accv = __builtin_amdgcn_mfma_f32_16x16x32_bf16(pa0, bv0, accv, 0,0,0);
        accv = __builtin_amdgcn_mfma_f32_16x16x32_bf16(pa1, bv1, accv, 0,0,0);
        if(q4 == hs){ oSel[0]=accv[0]; oSel[1]=accv[1]; oSel[2]=accv[2]; oSel[3]=accv[3]; }
      }
    }
    oC[cell][0] = oSel[0]*inv[0]; oC[cell][1] = oSel[1]*inv[1];
    oC[cell][2] = oSel[2]*inv[2]; oC[cell][3] = oSel[3]*inv[3];
  }
  __syncthreads();
  // ao -> Abuf rows [cellA px0..3, cellB px0..3], col = head*16 + d
  {
    const int col = (g*4 + q4)*16 + l15;
    ushort* ab = (ushort*)Abuf;
    #pragma unroll
    for(int cell = 0; cell < 2; cell++){
      #pragma unroll
      for(int reg = 0; reg < 4; reg++)
        ab[(cell*4 + reg)*ASTR + col] = (ushort)bfr(oC[cell][reg]);
    }
  }
  __syncthreads();

  // ---- proj GEMM + ls1*res -> xh, LN2 -> Abuf ----
  float xh[4][4];
  {
    // residual prefetch (L2-hot xt), replaces the old xvL LDS buffer
    float xres[4][4];
    #pragma unroll
    for(int nt = 0; nt < 4; nt++){
      const int col = (wave*4+nt)*16 + l15;
      #pragma unroll
      for(int r = 0; r < 4; r++){
        const int row = q4*4 + r;
        xres[nt][r] = (row < 8)
          ? xt_in[p0 + ((size_t)(row>>1)<<14) + (size_t)((row&1)<<7) + col] : 0.f;
      }
    }
    bf16x8 af[4];
    #pragma unroll
    for(int s = 0; s < 4; s++) af[s] = *(const bf16x8*)&Abuf[l15*ASTR + s*32 + q4*8];
    f32x4 acc[4];
    #pragma unroll
    for(int nt = 0; nt < 4; nt++){ acc[nt][0]=0.f; acc[nt][1]=0.f; acc[nt][2]=0.f; acc[nt][3]=0.f; }
    #pragma unroll
    for(int nt = 0; nt < 4; nt++){
      const int n = (wave*4+nt)*16 + l15;
      #pragma unroll
      for(int s = 0; s < 4; s++){
        bf16x8 bf = *(const bf16x8*)&packP[((s*128 + n)*4 + q4)*8];
        acc[nt] = __builtin_amdgcn_mfma_f32_16x16x32_bf16(af[s], bf, acc[nt], 0,0,0);
      }
    }
    float s1[4], s2[4];
    #pragma unroll
    for(int r = 0; r < 4; r++){ s1[r]=0.f; s2[r]=0.f; }
    #pragma unroll
    for(int nt = 0; nt < 4; nt++){
      const int col = (wave*4+nt)*16 + l15;
      const float bp = proj_b[col], l1 = ls1[col];
      #pragma unroll
      for(int r = 0; r < 4; r++){
        const float hx = xres[nt][r] + l1*(acc[nt][r] + bp);
        xh[nt][r] = hx; s1[r] += hx; s2[r] += hx*hx;
      }
    }
    rowred(s1, s2, red, wave, lane);
    #pragma unroll
    for(int nt = 0; nt < 4; nt++){
      const int col = (wave*4+nt)*16 + l15;
      const float g2 = n2g[col], be = n2b[col];
      #pragma unroll
      for(int r = 0; r < 4; r++){
        const int row = q4*4 + r;
        if(row < 8){
          const float mu = s1[r]*(1.f/128.f);
          const float var = s2[r]*(1.f/128.f) - mu*mu;
          Abuf[row*ASTR + col] =
            __float2bfloat16((xh[nt][r]-mu)*rsqrtf(var+1e-6f)*g2 + be);
        }
      }
    }
  }
  __syncthreads();

  // ---- fc1 GEMM (N=176) + midLN + gelu -> Abuf ----
  {
    bf16x8 af[4];
    #pragma unroll
    for(int s = 0; s < 4; s++) af[s] = *(const bf16x8*)&Abuf[l15*ASTR + s*32 + q4*8];
    const int NT1 = wave ? 5 : 6;
    f32x4 acc1[6];
    #pragma unroll
    for(int nt = 0; nt < 6; nt++){ acc1[nt][0]=0.f; acc1[nt][1]=0.f; acc1[nt][2]=0.f; acc1[nt][3]=0.f; }
    for(int nt = 0; nt < NT1; nt++){
      const int tI = wave ? (6 + nt) : nt;
      const int n = tI*16 + l15;
      #pragma unroll
      for(int s = 0; s < 4; s++){
        bf16x8 bf = *(const bf16x8*)&packF1[((s*176 + n)*4 + q4)*8];
        acc1[nt] = __builtin_amdgcn_mfma_f32_16x16x32_bf16(af[s], bf, acc1[nt], 0,0,0);
      }
    }
    float s1[4], s2[4];
    #pragma unroll
    for(int r = 0; r < 4; r++){ s1[r]=0.f; s2[r]=0.f; }
    for(int nt = 0; nt < NT1; nt++){
      const int tI = wave ? (6 + nt) : nt;
      const int col = tI*16 + l15;
      const float b1 = (col < 170) ? fc1_b[col] : 0.f;
      #pragma unroll
      for(int r = 0; r < 4; r++){
        const float vv = acc1[nt][r] + b1;
        acc1[nt][r] = vv; s1[r] += vv; s2[r] += vv*vv;
      }
    }
    rowred(s1, s2, red, wave, lane);
    for(int z = tid; z < 176; z += 128){
      const int row = z / 22, col = 170 + (z - (z/22)*22);
      Abuf[row*ASTR + col] = __float2bfloat16(0.f);
    }
    const float kA = 0.7978845608028654f, kB = 0.044715f;
    for(int nt = 0; nt < NT1; nt++){
      const int tI = wave ? (6 + nt) : nt;
      const int col = tI*16 + l15;
      if(col < 170){
        const float g2 = mg[col], be = mb[col];
        #pragma unroll
        for(int r = 0; r < 4; r++){
          const int row = q4*4 + r;
          if(row < 8){
            const float mu = s1[r]*(1.f/170.f);
            const float var = s2[r]*(1.f/170.f) - mu*mu;
            const float hn = (acc1[nt][r]-mu)*rsqrtf(var+1e-6f)*g2 + be;
            const float u = kA*(hn + kB*hn*hn*hn);
            const float gl = hn / (1.f + __expf(-2.f*u));
            Abuf[row*ASTR + col] = __float2bfloat16(gl);
          }
        }
      }
    }
  }
  __syncthreads();

  // ---- fc2 GEMM (K=192) + ls2*res -> out (B,C,H,W) directly ----
  {
    bf16x8 af[6];
    #pragma unroll
    for(int s = 0; s < 6; s++) af[s] = *(const bf16x8*)&Abuf[l15*ASTR + s*32 + q4*8];
    f32x4 acc[4];
    #pragma unroll
    for(int nt = 0; nt < 4; nt++){ acc[nt][0]=0.f; acc[nt][1]=0.f; acc[nt][2]=0.f; acc[nt][3]=0.f; }
    #pragma unroll
    for(int nt = 0; nt < 4; nt++){
      const int n = (wave*4+nt)*16 + l15;
      #pragma unroll
      for(int s = 0; s < 6; s++){
        bf16x8 bf = *(const bf16x8*)&packF2[((s*128 + n)*4 + q4)*8];
        acc[nt] = __builtin_amdgcn_mfma_f32_16x16x32_bf16(af[s], bf, acc[nt], 0,0,0);
      }
    }
    const size_t pixbase = (size_t)(4*ip)*128 + 2*jc;
    #pragma unroll
    for(int nt = 0; nt < 4; nt++){
      const int col = (wave*4+nt)*16 + l15;
      const float bf2 = fc2_b[col], l2 = ls2[col];
      const size_t obase = (size_t)(b*128 + col)*16384 + pixbase;
      #pragma unroll
      for(int r = 0; r < 4; r++){
        const int row = q4*4 + r;
        if(row < 8)
          out[obase + ((size_t)(row>>1)<<7) + (row&1)] =
            xh[nt][r] + l2*(acc[nt][r] + bf2);
      }
    }
  }
}

extern "C" void kernel_launch(void* const* d_in, const int* in_sizes, int n_in,
                              void* d_out, int out_size, void* d_ws, size_t ws_size,
                              hipStream_t stream){
  const float* x      = (const float*)d_in[0];
  const float* qkv_w  = (const float*)d_in[1];
  const float* qkv_b  = (const float*)d_in[2];
  const float* qg     = (const float*)d_in[3];
  const float* qb     = (const float*)d_in[4];
  const float* kg     = (const float*)d_in[5];
  const float* kb     = (const float*)d_in[6];
  const float* proj_w = (const float*)d_in[7];
  const float* proj_b = (const float*)d_in[8];
  const float* n1g    = (const float*)d_in[9];
  const float* n1b    = (const float*)d_in[10];
  const float* n2g    = (const float*)d_in[11];
  const float* n2b    = (const float*)d_in[12];
  const float* ls1    = (const float*)d_in[13];
  const float* ls2    = (const float*)d_in[14];
  const float* fc1_w  = (const float*)d_in[15];
  const float* fc1_b  = (const float*)d_in[16];
  const float* mg     = (const float*)d_in[17];
  const float* mb     = (const float*)d_in[18];
  const float* fc2_w  = (const float*)d_in[19];
  const float* fc2_b  = (const float*)d_in[20];

  float* ws  = (float*)d_ws;
  float* xt  = ws;
  float* kcb = ws + 4194304;
  float* vcb = ws + 5242880;
  BF* pk     = (BF*)(ws + 6291456);
  BF* packQ  = pk;
  BF* packP  = pk + 49152;
  BF* packF1 = pk + 65536;
  BF* packF2 = pk + 88064;

  k_pre <<<5048, 256, 0, stream>>>(x, qkv_w, proj_w, fc1_w, fc2_w, qkv_b,
                                   kg, kb, n1g, n1b, xt, pk, kcb, vcb);
  k_cell<<<4096, 128, 0, stream>>>(xt, packQ, packP, packF1, packF2,
                                   qkv_b, qg, qb, n1g, n1b, proj_b, ls1, ls2,
                                   n2g, n2b, fc1_b, mg, mb, fc2_b,
                                   kcb, vcb, (float*)d_out);
}

// Round 4
// 248.477 us; speedup vs baseline: 1.0351x; 1.0351x over previous
//
#include <hip/hip_runtime.h>
#include <hip/hip_bf16.h>

typedef __hip_bfloat16 BF;
typedef __attribute__((ext_vector_type(8))) short bf16x8;
typedef __attribute__((ext_vector_type(4))) float f32x4;
typedef __attribute__((ext_vector_type(4))) unsigned short us4;

// B=2, C=128, H=W=128, K=8, STRIDE=2, DIL=2, NH=8, dh=16, HID=170, Hc=Wc=64
// fp32 in / fp32 out. MFMA (bf16, fp32 acc) for dense GEMMs AND attention QK/PV.
// ws (floats): xt[0,4194304) kcb[+1048576) vcb[+1048576) ; packs (bf16) at 6291456

#define ASTR 200   // k_cell Abuf row stride (bf16)
#define KSTR 136   // k_pre(kv) Abuf row stride (bf16)

// fast f32 -> bf16 (RNE) returning raw bits
__device__ __forceinline__ short bfr(float f){
  union{float f; unsigned u;} c; c.f = f;
  const unsigned u = c.u + 0x7FFFu + ((c.u >> 16) & 1u);
  return (short)(u >> 16);
}
__device__ __forceinline__ bf16x8 pk8(float4 a, float4 b){
  bf16x8 r;
  r[0]=bfr(a.x); r[1]=bfr(a.y); r[2]=bfr(a.z); r[3]=bfr(a.w);
  r[4]=bfr(b.x); r[5]=bfr(b.y); r[6]=bfr(b.z); r[7]=bfr(b.w);
  return r;
}

// ---- 2-wave (128-thr) reductions for k_cell ----
__device__ __forceinline__ void gsum16(float v[16], float* red){
  #pragma unroll
  for(int s = 1; s < 64; s <<= 1){
    #pragma unroll
    for(int i = 0; i < 16; i++) v[i] += __shfl_xor(v[i], s);
  }
  const int wid = threadIdx.x >> 6;
  __syncthreads();
  if((threadIdx.x & 63) == 0){
    #pragma unroll
    for(int i = 0; i < 16; i++) red[wid*16 + i] = v[i];
  }
  __syncthreads();
  #pragma unroll
  for(int i = 0; i < 16; i++) v[i] = red[i] + red[16 + i];
}

__device__ __forceinline__ void rowred(float s1[4], float s2[4], float* red,
                                       int wave, int lane){
  #pragma unroll
  for(int m = 1; m < 16; m <<= 1){
    #pragma unroll
    for(int r = 0; r < 4; r++){ s1[r] += __shfl_xor(s1[r], m); s2[r] += __shfl_xor(s2[r], m); }
  }
  const int q4 = lane >> 4;
  __syncthreads();
  if((lane & 15) == 0){
    #pragma unroll
    for(int r = 0; r < 4; r++){
      red[wave*32 + q4*4 + r]      = s1[r];
      red[wave*32 + 16 + q4*4 + r] = s2[r];
    }
  }
  __syncthreads();
  #pragma unroll
  for(int r = 0; r < 4; r++){
    s1[r] = red[q4*4 + r]      + red[32 + q4*4 + r];
    s2[r] = red[16 + q4*4 + r] + red[48 + q4*4 + r];
  }
}

// ---- per-half (128-thr half of a 256-thr block) reductions for k_pre/kv ----
__device__ __forceinline__ void gsum16h(float v[16], float* red, int tid){
  #pragma unroll
  for(int s = 1; s < 64; s <<= 1){
    #pragma unroll
    for(int i = 0; i < 16; i++) v[i] += __shfl_xor(v[i], s);
  }
  const int wid = tid >> 6, half = tid >> 7;
  __syncthreads();
  if((tid & 63) == 0){
    #pragma unroll
    for(int i = 0; i < 16; i++) red[wid*16 + i] = v[i];
  }
  __syncthreads();
  #pragma unroll
  for(int i = 0; i < 16; i++) v[i] = red[half*32 + i] + red[half*32 + 16 + i];
}

__device__ __forceinline__ void rowredh(float s1[4], float s2[4], float* red, int tid){
  const int lane = tid & 63, wid = tid >> 6, half = tid >> 7;
  #pragma unroll
  for(int m = 1; m < 16; m <<= 1){
    #pragma unroll
    for(int r = 0; r < 4; r++){ s1[r] += __shfl_xor(s1[r], m); s2[r] += __shfl_xor(s2[r], m); }
  }
  const int q4 = lane >> 4;
  __syncthreads();
  if((lane & 15) == 0){
    #pragma unroll
    for(int r = 0; r < 4; r++){
      red[wid*32 + q4*4 + r]      = s1[r];
      red[wid*32 + 16 + q4*4 + r] = s2[r];
    }
  }
  __syncthreads();
  #pragma unroll
  for(int r = 0; r < 4; r++){
    s1[r] = red[half*64 + q4*4 + r]      + red[half*64 + 32 + q4*4 + r];
    s2[r] = red[half*64 + 16 + q4*4 + r] + red[half*64 + 48 + q4*4 + r];
  }
}

// ---- K_pre: fused {transpose x->xt | weight pack | coarse k,v} ----
// blocks [0,1024): 64x64 tiled transpose; [1024,1464): weight pack;
// [1464,1976): kv (reads x DIRECTLY, independent of transpose output).
__global__ void __launch_bounds__(256)
k_pre(const float* __restrict__ x,
      const float* __restrict__ qkv_w, const float* __restrict__ proj_w,
      const float* __restrict__ fc1_w, const float* __restrict__ fc2_w,
      const float* __restrict__ qkv_b,
      const float* __restrict__ kg, const float* __restrict__ kb,
      const float* __restrict__ n1g, const float* __restrict__ n1b,
      float* __restrict__ xt, BF* __restrict__ pk,
      float* __restrict__ kcb, float* __restrict__ vcb){
  __shared__ __align__(16) unsigned char sm[16640];
  const int bx = blockIdx.x, tid = threadIdx.x;

  if(bx < 1024){                       // ---- transpose x (B,C,H,W) -> xt (B,HW,C)
    float (*tile)[65] = (float(*)[65])sm;
    const int b = bx >> 9, r2 = bx & 511;
    const int pb = (r2 & 255) * 64, cb = (r2 >> 8) * 64;
    const int tx = tid & 63, ty = tid >> 6;
    #pragma unroll
    for(int r = 0; r < 64; r += 4)
      tile[cb ? (ty+r) : (ty+r)][tx] = x[(size_t)(b*128 + cb+ty+r)*16384 + pb + tx];
    __syncthreads();
    #pragma unroll
    for(int r = 0; r < 64; r += 4)
      xt[(size_t)((b<<14) + pb + ty + r)*128 + cb + tx] = tile[tx][ty+r];
    return;
  }
  if(bx < 1464){                       // ---- weight pack
    const int idx = (bx - 1024) * 256 + tid;
    if(idx >= 112640) return;
    float val;
    if(idx < 49152){
      const int reg = idx >> 14, l = idx & 16383;
      const int j = l & 7, q = (l>>3)&3, n = (l>>5)&127, s = l>>12;
      val = qkv_w[(reg*128 + n)*128 + (s*32 + q*8 + j)];
    } else if(idx < 65536){
      const int l = idx - 49152;
      const int j = l&7, q=(l>>3)&3, n=(l>>5)&127, s=l>>12;
      val = proj_w[n*128 + (s*32+q*8+j)];
    } else if(idx < 88064){
      const int l = idx - 65536;
      const int j = l&7, q=(l>>3)&3, rem = l>>5;
      const int n = rem % 176, s = rem / 176;
      const int k = s*32+q*8+j;
      val = (n < 170) ? fc1_w[n*128 + k] : 0.f;
    } else {
      const int l = idx - 88064;
      const int j = l&7, q=(l>>3)&3, n=(l>>5)&127, s=l>>12;
      const int k = s*32+q*8+j;
      val = (k < 170) ? fc2_w[n*170 + k] : 0.f;
    }
    pk[idx] = __float2bfloat16(val);
    return;
  }

  // ---- kv: 16 coarse px/block, two independent 128-thr halves ----
  const BF* packK = pk + 16384;
  const BF* packV = pk + 32768;
  BF* const Abuf = (BF*)sm;                    // 2 halves x [16][KSTR]
  float* const red = (float*)(sm + 8704);      // 128 floats
  const int bx2 = bx - 1464;
  const int lane = tid & 63, half = tid >> 7, wh = (tid >> 6) & 1, c = tid & 127;
  const int l15 = lane & 15, q4 = lane >> 4;
  const int cp0 = bx2 * 16;
  const int b = cp0 >> 12, ic = (cp0 & 4095) >> 6, jb = cp0 & 63;
  BF* const AbufH = Abuf + half*16*KSTR;

  float xv[8];
  {
    const size_t off = (size_t)(b*128 + c)*16384 + (size_t)(2*ic)*128 + 2*(jb + half*8);
    const float4* xp4 = (const float4*)(x + off);
    const float4 f0 = xp4[0], f1 = xp4[1], f2 = xp4[2], f3 = xp4[3];
    xv[0]=f0.x; xv[1]=f0.z; xv[2]=f1.x; xv[3]=f1.z;
    xv[4]=f2.x; xv[5]=f2.z; xv[6]=f3.x; xv[7]=f3.z;
  }
  float st[16];
  #pragma unroll
  for(int r = 0; r < 8; r++){ st[r] = xv[r]; st[8+r] = xv[r]*xv[r]; }
  gsum16h(st, red, tid);
  {
    const float g = n1g[c], be = n1b[c];
    #pragma unroll
    for(int r = 0; r < 8; r++){
      const float mu = st[r]*(1.f/128.f);
      const float var = st[8+r]*(1.f/128.f) - mu*mu;
      AbufH[r*KSTR + c] = __float2bfloat16((xv[r]-mu)*rsqrtf(var+1e-6f)*g + be);
    }
  }
  __syncthreads();
  bf16x8 af[4];
  #pragma unroll
  for(int s = 0; s < 4; s++) af[s] = *(const bf16x8*)&AbufH[l15*KSTR + s*32 + q4*8];

  // ---- k GEMM ----
  f32x4 acc[4];
  #pragma unroll
  for(int nt = 0; nt < 4; nt++){ acc[nt][0]=0.f; acc[nt][1]=0.f; acc[nt][2]=0.f; acc[nt][3]=0.f; }
  #pragma unroll
  for(int nt = 0; nt < 4; nt++){
    const int n = (wh*4+nt)*16 + l15;
    #pragma unroll
    for(int s = 0; s < 4; s++){
      bf16x8 bf = *(const bf16x8*)&packK[((s*128 + n)*4 + q4)*8];
      acc[nt] = __builtin_amdgcn_mfma_f32_16x16x32_bf16(af[s], bf, acc[nt], 0,0,0);
    }
  }
  float s1[4], s2[4];
  #pragma unroll
  for(int r = 0; r < 4; r++){ s1[r]=0.f; s2[r]=0.f; }
  #pragma unroll
  for(int nt = 0; nt < 4; nt++){
    const float colb = qkv_b[128 + (wh*4+nt)*16 + l15];
    #pragma unroll
    for(int r = 0; r < 4; r++){
      const float vv = acc[nt][r] + colb;
      acc[nt][r] = vv; s1[r] += vv; s2[r] += vv*vv;
    }
  }
  rowredh(s1, s2, red, tid);
  #pragma unroll
  for(int nt = 0; nt < 4; nt++){
    const int col = (wh*4+nt)*16 + l15;
    const float g = kg[col], be = kb[col];
    #pragma unroll
    for(int r = 0; r < 4; r++){
      const int row = q4*4 + r;
      if(row < 8){
        const float mu = s1[r]*(1.f/128.f);
        const float var = s2[r]*(1.f/128.f) - mu*mu;
        kcb[(size_t)(cp0 + half*8 + row)*128 + col] = (acc[nt][r]-mu)*rsqrtf(var+1e-6f)*g + be;
      }
    }
  }
  // ---- v GEMM ----
  #pragma unroll
  for(int nt = 0; nt < 4; nt++){ acc[nt][0]=0.f; acc[nt][1]=0.f; acc[nt][2]=0.f; acc[nt][3]=0.f; }
  #pragma unroll
  for(int nt = 0; nt < 4; nt++){
    const int n = (wh*4+nt)*16 + l15;
    #pragma unroll
    for(int s = 0; s < 4; s++){
      bf16x8 bf = *(const bf16x8*)&packV[((s*128 + n)*4 + q4)*8];
      acc[nt] = __builtin_amdgcn_mfma_f32_16x16x32_bf16(af[s], bf, acc[nt], 0,0,0);
    }
  }
  #pragma unroll
  for(int nt = 0; nt < 4; nt++){
    const int col = (wh*4+nt)*16 + l15;
    const float bv = qkv_b[256 + col];
    #pragma unroll
    for(int r = 0; r < 4; r++){
      const int row = q4*4 + r;
      if(row < 8) vcb[(size_t)(cp0 + half*8 + row)*128 + col] = acc[nt][r] + bv;
    }
  }
}

// ---- K_cell: fused per-2-cells (8 pixels) block, all-MFMA ----
// LDS 15744B -> 10 blocks/CU: uni 9216 (Abuf[16][200] U 2 waves x {Vt 1152,
// Pb 1152}) + xvL 4096 + qnH 2176 (red aliased) + cidx 256.
// Coalesced xt output (transpose-out is a separate kernel).
__global__ void __launch_bounds__(128, 5)
k_cell(const float* __restrict__ xt_in,
       const BF* __restrict__ packQ, const BF* __restrict__ packP,
       const BF* __restrict__ packF1, const BF* __restrict__ packF2,
       const float* __restrict__ qkv_b,
       const float* __restrict__ qg, const float* __restrict__ qb,
       const float* __restrict__ n1g, const float* __restrict__ n1b,
       const float* __restrict__ proj_b,
       const float* __restrict__ ls1, const float* __restrict__ ls2,
       const float* __restrict__ n2g, const float* __restrict__ n2b,
       const float* __restrict__ fc1_b,
       const float* __restrict__ mg, const float* __restrict__ mb,
       const float* __restrict__ fc2_b,
       const float* __restrict__ kcb, const float* __restrict__ vcb,
       float* __restrict__ xt_out){
  __shared__ __align__(16) BF uni[4608];      // Abuf[16][ASTR] U per-wave attn {Vt,Pb}
  BF* const Abuf = uni;
  __shared__ float xvL[8*128];
  __shared__ __align__(16) ushort qnH[1088];  // [cell][136ch_pad][4px] bf16 (red aliases first 256B)
  __shared__ ushort cidx2[128];               // [cell][64] safe coarse-px linear idx
  float* const red = (float*)qnH;
  const int tid = threadIdx.x, wave = tid>>6, lane = tid&63;
  const int l15 = lane & 15, q4 = lane >> 4;

  const int bx = blockIdx.x;
  const int b = bx >> 11, rem = bx & 2047, ip = rem >> 6, jc = rem & 63;
  const int icA = 2*ip, icB = 2*ip + 1;
  const size_t p0 = (size_t)b*16384*128 + ((size_t)(4*ip)*128 + 2*jc)*128;
  float xv[8];
  #pragma unroll
  for(int r = 0; r < 8; r++){
    const size_t pr = p0 + ((size_t)(r>>1)<<14) + (size_t)((r&1)<<7);
    xv[r] = xt_in[pr + tid]; xvL[r*128 + tid] = xv[r];
  }

  // ---- LN1 (single fused reduction) ----
  float st[16];
  #pragma unroll
  for(int r = 0; r < 8; r++){ st[r] = xv[r]; st[8+r] = xv[r]*xv[r]; }
  gsum16(st, red);
  {
    const float g = n1g[tid], be = n1b[tid];
    #pragma unroll
    for(int r = 0; r < 8; r++){
      const float mu = st[r]*(1.f/128.f);
      const float var = st[8+r]*(1.f/128.f) - mu*mu;
      Abuf[r*ASTR + tid] = __float2bfloat16((xv[r]-mu)*rsqrtf(var+1e-6f)*g + be);
    }
  }
  if(tid < 64){
    const int i = tid >> 3, j = tid & 7;
    const int rj0 = jc + 2*j - 8;
    const bool vj0 = (rj0 >= 0) && (rj0 < 64);
    const int riA = icA + 2*i - 8, riB = icB + 2*i - 8;
    cidx2[tid]      = (vj0 && riA >= 0 && riA < 64) ? (ushort)(b*4096 + riA*64 + rj0) : (ushort)0;
    cidx2[64 + tid] = (vj0 && riB >= 0 && riB < 64) ? (ushort)(b*4096 + riB*64 + rj0) : (ushort)0;
  }
  __syncthreads();

  // ---- q GEMM + q-LN -> qnH (bf16) ----
  {
    bf16x8 af[4];
    #pragma unroll
    for(int s = 0; s < 4; s++) af[s] = *(const bf16x8*)&Abuf[l15*ASTR + s*32 + q4*8];
    f32x4 acc[4];
    #pragma unroll
    for(int nt = 0; nt < 4; nt++){ acc[nt][0]=0.f; acc[nt][1]=0.f; acc[nt][2]=0.f; acc[nt][3]=0.f; }
    #pragma unroll
    for(int nt = 0; nt < 4; nt++){
      const int n = (wave*4+nt)*16 + l15;
      #pragma unroll
      for(int s = 0; s < 4; s++){
        bf16x8 bf = *(const bf16x8*)&packQ[((s*128 + n)*4 + q4)*8];
        acc[nt] = __builtin_amdgcn_mfma_f32_16x16x32_bf16(af[s], bf, acc[nt], 0,0,0);
      }
    }
    float s1[4], s2[4];
    #pragma unroll
    for(int r = 0; r < 4; r++){ s1[r]=0.f; s2[r]=0.f; }
    #pragma unroll
    for(int nt = 0; nt < 4; nt++){
      const float cb2 = qkv_b[(wave*4+nt)*16 + l15];
      #pragma unroll
      for(int r = 0; r < 4; r++){
        const float vv = acc[nt][r] + cb2;
        acc[nt][r] = vv; s1[r] += vv; s2[r] += vv*vv;
      }
    }
    rowred(s1, s2, red, wave, lane);
    const bool wq = (q4 < 2);
    us4 tw[4];
    if(wq){
      float mu[4], rs[4];
      #pragma unroll
      for(int r = 0; r < 4; r++){
        mu[r] = s1[r]*(1.f/128.f);
        rs[r] = rsqrtf(s2[r]*(1.f/128.f) - mu[r]*mu[r] + 1e-6f);
      }
      #pragma unroll
      for(int nt = 0; nt < 4; nt++){
        const int col = (wave*4+nt)*16 + l15;
        const float g = qg[col], be = qb[col];
        tw[nt][0] = (unsigned short)bfr((acc[nt][0]-mu[0])*rs[0]*g + be);
        tw[nt][1] = (unsigned short)bfr((acc[nt][1]-mu[1])*rs[1]*g + be);
        tw[nt][2] = (unsigned short)bfr((acc[nt][2]-mu[2])*rs[2]*g + be);
        tw[nt][3] = (unsigned short)bfr((acc[nt][3]-mu[3])*rs[3]*g + be);
      }
    }
    __syncthreads();            // red (aliased with qnH) fully read by all waves
    if(wq){
      #pragma unroll
      for(int nt = 0; nt < 4; nt++){
        const int col = (wave*4+nt)*16 + l15;
        const int colp = col + (col >> 4);
        *(us4*)(qnH + q4*544 + colp*4) = tw[nt];
      }
    }
  }
  __syncthreads();

  // ---- attention, all-MFMA, wave-private heads ----
  const int g = wave;
  const int hsub = l15 >> 2, px = l15 & 3;
  const int par = q4 >> 1, dbase = (q4 & 1) * 8;
  BF* const attw = uni + wave*2304;
  ushort* const Vt = (ushort*)attw;            // 1 slot [16][72]
  ushort* const Pb = (ushort*)(attw + 1152);   // [16][72]
  const int i0 = l15 >> 3;
  const int rj = jc + 2*(l15 & 7) - 8;
  const bool vj = (rj >= 0) && (rj < 64);

  f32x4 oC[2];
  #pragma unroll
  for(int cell = 0; cell < 2; cell++){
    const ushort* cidx = cidx2 + cell*64;
    const ushort* qp = qnH + cell*544;
    const int ic = cell ? icB : icA;
    float madd[4];
    #pragma unroll
    for(int nt = 0; nt < 4; nt++){
      const int ri = ic + 2*(nt*2 + i0) - 8;
      madd[nt] = (vj && ri >= 0 && ri < 64) ? 0.f : -1e30f;
    }
    // block-diagonal q A-fragments
    bf16x8 afq0, afq1;
    {
      const int idx0 = (g*64 + hsub*16 + dbase + (g*4 + hsub))*4 + px;
      short bq[8];
      #pragma unroll
      for(int j = 0; j < 8; j++) bq[j] = (short)qp[idx0 + 4*j];
      const bool a0 = (par == hsub), a1 = ((2 + par) == hsub);
      #pragma unroll
      for(int j = 0; j < 8; j++){
        afq0[j] = a0 ? bq[j] : (short)0;
        afq1[j] = a1 ? bq[j] : (short)0;
      }
    }
    // ---- QK: 8 MFMA ----
    f32x4 accq[4];
    #pragma unroll
    for(int nt = 0; nt < 4; nt++){ accq[nt][0]=0.f; accq[nt][1]=0.f; accq[nt][2]=0.f; accq[nt][3]=0.f; }
    #pragma unroll
    for(int nt = 0; nt < 4; nt++){
      const float* kp = kcb + ((size_t)cidx[nt*16 + l15] << 7) + g*64 + q4*8;
      const float4 k00 = *(const float4*)kp;
      const float4 k01 = *(const float4*)(kp + 4);
      const float4 k10 = *(const float4*)(kp + 32);
      const float4 k11 = *(const float4*)(kp + 36);
      accq[nt] = __builtin_amdgcn_mfma_f32_16x16x32_bf16(afq0, pk8(k00,k01), accq[nt], 0,0,0);
      accq[nt] = __builtin_amdgcn_mfma_f32_16x16x32_bf16(afq1, pk8(k10,k11), accq[nt], 0,0,0);
    }
    // ---- softmax in-register; unnormalized e (bf16) -> Pb ----
    float inv[4];
    #pragma unroll
    for(int reg = 0; reg < 4; reg++){
      const float s0 = accq[0][reg]*0.25f + madd[0];
      const float s1 = accq[1][reg]*0.25f + madd[1];
      const float s2 = accq[2][reg]*0.25f + madd[2];
      const float s3 = accq[3][reg]*0.25f + madd[3];
      float m = fmaxf(fmaxf(s0,s1), fmaxf(s2,s3));
      #pragma unroll
      for(int sft = 1; sft < 16; sft <<= 1) m = fmaxf(m, __shfl_xor(m, sft));
      const float e0 = __expf(s0-m), e1 = __expf(s1-m);
      const float e2 = __expf(s2-m), e3 = __expf(s3-m);
      ushort* pr = Pb + (q4*4 + reg)*72 + l15;
      pr[0]  = (ushort)bfr(e0);
      pr[16] = (ushort)bfr(e1);
      pr[32] = (ushort)bfr(e2);
      pr[48] = (ushort)bfr(e3);
      float es = e0+e1+e2+e3;
      #pragma unroll
      for(int sft = 1; sft < 16; sft <<= 1) es += __shfl_xor(es, sft);
      inv[reg] = 1.f/es;
    }
    const bf16x8 pa0 = *(const bf16x8*)(Pb + l15*72 + q4*8);
    const bf16x8 pa1 = *(const bf16x8*)(Pb + l15*72 + 32 + q4*8);

    // ---- PV: per head, stage V (1 slot) + 2 MFMA; select own head's acc ----
    f32x4 oSel; oSel[0]=0.f; oSel[1]=0.f; oSel[2]=0.f; oSel[3]=0.f;
    #pragma unroll
    for(int hs = 0; hs < 4; hs++){
      const int h = g*4 + hs;
      float4 vv[4];
      #pragma unroll
      for(int it = 0; it < 4; it++)
        vv[it] = *(const float4*)(vcb + ((size_t)cidx[l15*4 + it] << 7) + h*16 + q4*4);
      #pragma unroll
      for(int dd = 0; dd < 4; dd++){
        us4 w;
        w[0] = (unsigned short)bfr(((const float*)&vv[0])[dd]);
        w[1] = (unsigned short)bfr(((const float*)&vv[1])[dd]);
        w[2] = (unsigned short)bfr(((const float*)&vv[2])[dd]);
        w[3] = (unsigned short)bfr(((const float*)&vv[3])[dd]);
        *(us4*)(Vt + (q4*4 + dd)*72 + l15*4) = w;
      }
      const bf16x8 bv0 = *(const bf16x8*)(Vt + l15*72 + q4*8);
      const bf16x8 bv1 = *(const bf16x8*)(Vt + l15*72 + 32 + q4*8);
      f32x4 accv; accv[0]=0.f; accv[1]=0.f; accv[2]=0.f; accv[3]=0.f;
      accv = __builtin_amdgcn_mfma_f32_16x16x32_bf16(pa0, bv0, accv, 0,0,0);
      accv = __builtin_amdgcn_mfma_f32_16x16x32_bf16(pa1, bv1, accv, 0,0,0);
      if(q4 == hs){ oSel[0]=accv[0]; oSel[1]=accv[1]; oSel[2]=accv[2]; oSel[3]=accv[3]; }
    }
    oC[cell][0] = oSel[0]*inv[0]; oC[cell][1] = oSel[1]*inv[1];
    oC[cell][2] = oSel[2]*inv[2]; oC[cell][3] = oSel[3]*inv[3];
  }
  __syncthreads();
  // ao -> Abuf rows [cellA px0..3, cellB px0..3], col = head*16 + d
  {
    const int col = (g*4 + q4)*16 + l15;
    ushort* ab = (ushort*)Abuf;
    #pragma unroll
    for(int cell = 0; cell < 2; cell++){
      #pragma unroll
      for(int reg = 0; reg < 4; reg++)
        ab[(cell*4 + reg)*ASTR + col] = (ushort)bfr(oC[cell][reg]);
    }
  }
  __syncthreads();

  // ---- proj GEMM + ls1*res -> xh, LN2 -> Abuf ----
  float xh[4][4];
  {
    bf16x8 af[4];
    #pragma unroll
    for(int s = 0; s < 4; s++) af[s] = *(const bf16x8*)&Abuf[l15*ASTR + s*32 + q4*8];
    f32x4 acc[4];
    #pragma unroll
    for(int nt = 0; nt < 4; nt++){ acc[nt][0]=0.f; acc[nt][1]=0.f; acc[nt][2]=0.f; acc[nt][3]=0.f; }
    #pragma unroll
    for(int nt = 0; nt < 4; nt++){
      const int n = (wave*4+nt)*16 + l15;
      #pragma unroll
      for(int s = 0; s < 4; s++){
        bf16x8 bf = *(const bf16x8*)&packP[((s*128 + n)*4 + q4)*8];
        acc[nt] = __builtin_amdgcn_mfma_f32_16x16x32_bf16(af[s], bf, acc[nt], 0,0,0);
      }
    }
    float s1[4], s2[4];
    #pragma unroll
    for(int r = 0; r < 4; r++){ s1[r]=0.f; s2[r]=0.f; }
    #pragma unroll
    for(int nt = 0; nt < 4; nt++){
      const int col = (wave*4+nt)*16 + l15;
      const float bp = proj_b[col], l1 = ls1[col];
      #pragma unroll
      for(int r = 0; r < 4; r++){
        const int row = q4*4 + r;
        const float xvv = (row < 8) ? xvL[row*128 + col] : 0.f;
        const float hx = xvv + l1*(acc[nt][r] + bp);
        xh[nt][r] = hx; s1[r] += hx; s2[r] += hx*hx;
      }
    }
    rowred(s1, s2, red, wave, lane);
    #pragma unroll
    for(int nt = 0; nt < 4; nt++){
      const int col = (wave*4+nt)*16 + l15;
      const float g2 = n2g[col], be = n2b[col];
      #pragma unroll
      for(int r = 0; r < 4; r++){
        const int row = q4*4 + r;
        if(row < 8){
          const float mu = s1[r]*(1.f/128.f);
          const float var = s2[r]*(1.f/128.f) - mu*mu;
          Abuf[row*ASTR + col] =
            __float2bfloat16((xh[nt][r]-mu)*rsqrtf(var+1e-6f)*g2 + be);
        }
      }
    }
  }
  __syncthreads();

  // ---- fc1 GEMM (N=176) + midLN + gelu -> Abuf ----
  {
    bf16x8 af[4];
    #pragma unroll
    for(int s = 0; s < 4; s++) af[s] = *(const bf16x8*)&Abuf[l15*ASTR + s*32 + q4*8];
    const int NT1 = wave ? 5 : 6;
    f32x4 acc1[6];
    #pragma unroll
    for(int nt = 0; nt < 6; nt++){ acc1[nt][0]=0.f; acc1[nt][1]=0.f; acc1[nt][2]=0.f; acc1[nt][3]=0.f; }
    for(int nt = 0; nt < NT1; nt++){
      const int tI = wave ? (6 + nt) : nt;
      const int n = tI*16 + l15;
      #pragma unroll
      for(int s = 0; s < 4; s++){
        bf16x8 bf = *(const bf16x8*)&packF1[((s*176 + n)*4 + q4)*8];
        acc1[nt] = __builtin_amdgcn_mfma_f32_16x16x32_bf16(af[s], bf, acc1[nt], 0,0,0);
      }
    }
    float s1[4], s2[4];
    #pragma unroll
    for(int r = 0; r < 4; r++){ s1[r]=0.f; s2[r]=0.f; }
    for(int nt = 0; nt < NT1; nt++){
      const int tI = wave ? (6 + nt) : nt;
      const int col = tI*16 + l15;
      const float b1 = (col < 170) ? fc1_b[col] : 0.f;
      #pragma unroll
      for(int r = 0; r < 4; r++){
        const float vv = acc1[nt][r] + b1;
        acc1[nt][r] = vv; s1[r] += vv; s2[r] += vv*vv;
      }
    }
    rowred(s1, s2, red, wave, lane);
    for(int z = tid; z < 176; z += 128){
      const int row = z / 22, col = 170 + (z - (z/22)*22);
      Abuf[row*ASTR + col] = __float2bfloat16(0.f);
    }
    const float kA = 0.7978845608028654f, kB = 0.044715f;
    for(int nt = 0; nt < NT1; nt++){
      const int tI = wave ? (6 + nt) : nt;
      const int col = tI*16 + l15;
      if(col < 170){
        const float g2 = mg[col], be = mb[col];
        #pragma unroll
        for(int r = 0; r < 4; r++){
          const int row = q4*4 + r;
          if(row < 8){
            const float mu = s1[r]*(1.f/170.f);
            const float var = s2[r]*(1.f/170.f) - mu*mu;
            const float hn = (acc1[nt][r]-mu)*rsqrtf(var+1e-6f)*g2 + be;
            const float u = kA*(hn + kB*hn*hn*hn);
            const float gl = hn / (1.f + __expf(-2.f*u));
            Abuf[row*ASTR + col] = __float2bfloat16(gl);
          }
        }
      }
    }
  }
  __syncthreads();

  // ---- fc2 GEMM (K=192) + ls2*res -> xt (coalesced) ----
  {
    bf16x8 af[6];
    #pragma unroll
    for(int s = 0; s < 6; s++) af[s] = *(const bf16x8*)&Abuf[l15*ASTR + s*32 + q4*8];
    f32x4 acc[4];
    #pragma unroll
    for(int nt = 0; nt < 4; nt++){ acc[nt][0]=0.f; acc[nt][1]=0.f; acc[nt][2]=0.f; acc[nt][3]=0.f; }
    #pragma unroll
    for(int nt = 0; nt < 4; nt++){
      const int n = (wave*4+nt)*16 + l15;
      #pragma unroll
      for(int s = 0; s < 6; s++){
        bf16x8 bf = *(const bf16x8*)&packF2[((s*128 + n)*4 + q4)*8];
        acc[nt] = __builtin_amdgcn_mfma_f32_16x16x32_bf16(af[s], bf, acc[nt], 0,0,0);
      }
    }
    #pragma unroll
    for(int nt = 0; nt < 4; nt++){
      const int col = (wave*4+nt)*16 + l15;
      const float bf2 = fc2_b[col], l2 = ls2[col];
      #pragma unroll
      for(int r = 0; r < 4; r++){
        const int row = q4*4 + r;
        if(row < 8)
          xt_out[p0 + ((size_t)(row>>1)<<14) + (size_t)((row&1)<<7) + col] =
            xh[nt][r] + l2*(acc[nt][r] + bf2);
      }
    }
  }
}

// ---- K_out: 64x64 tiled transpose xt (B,HW,C) -> out (B,C,H,W) ----
__global__ void __launch_bounds__(256)
k_tout(const float* __restrict__ xt, float* __restrict__ out){
  __shared__ float tile[64][65];
  const int bx = blockIdx.x, tid = threadIdx.x;
  const int b = bx >> 9, r2 = bx & 511;
  const int pb = (r2 & 255) * 64, cb = (r2 >> 8) * 64;
  const int tx = tid & 63, ty = tid >> 6;
  #pragma unroll
  for(int r = 0; r < 64; r += 4)
    tile[ty+r][tx] = xt[(size_t)((b<<14) + pb + ty + r)*128 + cb + tx];
  __syncthreads();
  #pragma unroll
  for(int r = 0; r < 64; r += 4)
    out[(size_t)(b*128 + cb + ty + r)*16384 + pb + tx] = tile[tx][ty+r];
}

extern "C" void kernel_launch(void* const* d_in, const int* in_sizes, int n_in,
                              void* d_out, int out_size, void* d_ws, size_t ws_size,
                              hipStream_t stream){
  const float* x      = (const float*)d_in[0];
  const float* qkv_w  = (const float*)d_in[1];
  const float* qkv_b  = (const float*)d_in[2];
  const float* qg     = (const float*)d_in[3];
  const float* qb     = (const float*)d_in[4];
  const float* kg     = (const float*)d_in[5];
  const float* kb     = (const float*)d_in[6];
  const float* proj_w = (const float*)d_in[7];
  const float* proj_b = (const float*)d_in[8];
  const float* n1g    = (const float*)d_in[9];
  const float* n1b    = (const float*)d_in[10];
  const float* n2g    = (const float*)d_in[11];
  const float* n2b    = (const float*)d_in[12];
  const float* ls1    = (const float*)d_in[13];
  const float* ls2    = (const float*)d_in[14];
  const float* fc1_w  = (const float*)d_in[15];
  const float* fc1_b  = (const float*)d_in[16];
  const float* mg     = (const float*)d_in[17];
  const float* mb     = (const float*)d_in[18];
  const float* fc2_w  = (const float*)d_in[19];
  const float* fc2_b  = (const float*)d_in[20];

  float* ws  = (float*)d_ws;
  float* xt  = ws;
  float* kcb = ws + 4194304;
  float* vcb = ws + 5242880;
  BF* pk     = (BF*)(ws + 6291456);
  BF* packQ  = pk;
  BF* packP  = pk + 49152;
  BF* packF1 = pk + 65536;
  BF* packF2 = pk + 88064;

  k_pre <<<1976, 256, 0, stream>>>(x, qkv_w, proj_w, fc1_w, fc2_w, qkv_b,
                                   kg, kb, n1g, n1b, xt, pk, kcb, vcb);
  k_cell<<<4096, 128, 0, stream>>>(xt, packQ, packP, packF1, packF2,
                                   qkv_b, qg, qb, n1g, n1b, proj_b, ls1, ls2,
                                   n2g, n2b, fc1_b, mg, mb, fc2_b,
                                   kcb, vcb, xt);
  k_tout<<<1024, 256, 0, stream>>>(xt, (float*)d_out);
}